// Round 2
// baseline (1026.416 us; speedup 1.0000x reference)
//
#include <hip/hip_runtime.h>

// Problem constants
#define B_   4
#define L_   2048
#define DIN  1024
#define DOUT 1024
#define H_   16
#define DH_  64
#define M_   (B_ * L_)   // 8192 rows

typedef __bf16 bf16x8 __attribute__((ext_vector_type(8)));
typedef float  f32x4  __attribute__((ext_vector_type(4)));

__device__ __forceinline__ float bf2f(unsigned short u) {
  union { unsigned int i; float f; } x; x.i = ((unsigned int)u) << 16; return x.f;
}
__device__ __forceinline__ unsigned short f2bf(float f) {
  union { float f; unsigned int i; } x; x.f = f;
  unsigned int r = x.i + 0x7FFFu + ((x.i >> 16) & 1u);
  return (unsigned short)(r >> 16);
}

// DPP cross-lane add (VALU latency, no DS pipe). 0xB1=quad_perm[1,0,3,2],
// 0x4E=quad_perm[2,3,0,1], 0x124=row_ror:4, 0x128=row_ror:8 -> 16-lane allreduce.
template <int CTRL>
__device__ __forceinline__ float dpp_add(float x) {
  int v = __builtin_amdgcn_update_dpp(0, __float_as_int(x), CTRL, 0xF, 0xF, false);
  return x + __int_as_float(v);
}
// 32-lane allreduce: 16-lane DPP allreduce, then xor-16 exchange via
// ds_swizzle BitMode (offset = (xor=16)<<10 | and=0x1F = 0x401F); ds_swizzle
// operates within 32-lane groups, so both wave halves reduce independently.
__device__ __forceinline__ float row32_allreduce(float x) {
  x = dpp_add<0xB1>(x);
  x = dpp_add<0x4E>(x);
  x = dpp_add<0x124>(x);
  x = dpp_add<0x128>(x);
  x += __int_as_float(__builtin_amdgcn_ds_swizzle(__float_as_int(x), 0x401F));
  return x;
}

// ---------------------------------------------------------------------------
// fp32 -> (hi, lo) bf16 split: hi = bf16(x), lo = bf16(x - hi).
// ---------------------------------------------------------------------------
__global__ __launch_bounds__(256)
void cast_hilo(const float* __restrict__ in,
               unsigned short* __restrict__ hi,
               unsigned short* __restrict__ lo, int n)
{
  int i = (blockIdx.x * 256 + threadIdx.x) * 8;
  int stride = gridDim.x * 256 * 8;
  for (; i < n; i += stride) {
    float4 a = *(const float4*)(in + i);
    float4 b = *(const float4*)(in + i + 4);
    float v[8] = {a.x, a.y, a.z, a.w, b.x, b.y, b.z, b.w};
    ushort4 h0, h1, l0, l1;
    unsigned short hh[8], ll[8];
#pragma unroll
    for (int j = 0; j < 8; j++) {
      hh[j] = f2bf(v[j]);
      ll[j] = f2bf(v[j] - bf2f(hh[j]));
    }
    h0 = {hh[0], hh[1], hh[2], hh[3]}; h1 = {hh[4], hh[5], hh[6], hh[7]};
    l0 = {ll[0], ll[1], ll[2], ll[3]}; l1 = {ll[4], ll[5], ll[6], ll[7]};
    *(ushort4*)(hi + i) = h0; *(ushort4*)(hi + i + 4) = h1;
    *(ushort4*)(lo + i) = l0; *(ushort4*)(lo + i + 4) = l1;
  }
}

// ---------------------------------------------------------------------------
// GEMM core: C[M,N] = A[M,K] @ W[N,K]^T (+bias), A/W as hi/lo bf16 pairs.
// acc = hi*hi + lo*hi + hi*lo (3 MFMAs). 128x128 tile, BK=64, 4 waves 2x2.
// LDS rows padded to 72 ushort (144 B = 36 banks): consecutive rows shift by
// 4 banks, so the 16-lane fragment read (same col, rows r..r+15) is 2-way max
// (free) instead of the 16-way conflict (5.7x) of an unpadded 128 B stride.
// ---------------------------------------------------------------------------
#define LPAD 72
template <typename OutT>
__device__ __forceinline__
void gemm_hilo_core(const unsigned short* __restrict__ Ahi,
                    const unsigned short* __restrict__ Alo,
                    const unsigned short* __restrict__ Whi,
                    const unsigned short* __restrict__ Wlo,
                    OutT* __restrict__ C,
                    const float* __restrict__ bias,
                    int K, int N, int m0, int n0)
{
  __shared__ unsigned short AsH[128][LPAD];
  __shared__ unsigned short AsL[128][LPAD];
  __shared__ unsigned short BsH[128][LPAD];
  __shared__ unsigned short BsL[128][LPAD];
  const int t = threadIdx.x;
  const int w = t >> 6;
  const int lane = t & 63;
  const int wm = (w >> 1) * 64, wn = (w & 1) * 64;
  const int l15 = lane & 15, quad = lane >> 4;

  f32x4 acc[4][4] = {};

  for (int k0 = 0; k0 < K; k0 += 64) {
#pragma unroll
    for (int i = 0; i < 4; i++) {
      int c = t + 256 * i;
      int row = c >> 3;
      int col = (c & 7) * 8;
      size_t ga = (size_t)(m0 + row) * K + k0 + col;
      size_t gb = (size_t)(n0 + row) * K + k0 + col;
      *(uint4*)(&AsH[row][col]) = *(const uint4*)(Ahi + ga);
      *(uint4*)(&AsL[row][col]) = *(const uint4*)(Alo + ga);
      *(uint4*)(&BsH[row][col]) = *(const uint4*)(Whi + gb);
      *(uint4*)(&BsL[row][col]) = *(const uint4*)(Wlo + gb);
    }
    __syncthreads();
#pragma unroll
    for (int kh = 0; kh < 2; kh++) {
      bf16x8 ah[4], al[4], bh[4], bl[4];
#pragma unroll
      for (int i = 0; i < 4; i++) {
        union U { uint4 u; bf16x8 v; } u0, u1, u2, u3;
        u0.u = *(const uint4*)(&AsH[wm + i * 16 + l15][kh * 32 + quad * 8]);
        u1.u = *(const uint4*)(&AsL[wm + i * 16 + l15][kh * 32 + quad * 8]);
        u2.u = *(const uint4*)(&BsH[wn + i * 16 + l15][kh * 32 + quad * 8]);
        u3.u = *(const uint4*)(&BsL[wn + i * 16 + l15][kh * 32 + quad * 8]);
        ah[i] = u0.v; al[i] = u1.v; bh[i] = u2.v; bl[i] = u3.v;
      }
#pragma unroll
      for (int mt = 0; mt < 4; mt++)
#pragma unroll
        for (int nt = 0; nt < 4; nt++) {
          acc[mt][nt] = __builtin_amdgcn_mfma_f32_16x16x32_bf16(ah[mt], bh[nt], acc[mt][nt], 0, 0, 0);
          acc[mt][nt] = __builtin_amdgcn_mfma_f32_16x16x32_bf16(al[mt], bh[nt], acc[mt][nt], 0, 0, 0);
          acc[mt][nt] = __builtin_amdgcn_mfma_f32_16x16x32_bf16(ah[mt], bl[nt], acc[mt][nt], 0, 0, 0);
        }
    }
    __syncthreads();
  }

#pragma unroll
  for (int mt = 0; mt < 4; mt++) {
#pragma unroll
    for (int nt = 0; nt < 4; nt++) {
      int n = n0 + wn + nt * 16 + l15;
      float bv = bias ? bias[n] : 0.0f;
#pragma unroll
      for (int r = 0; r < 4; r++) {
        int m = m0 + wm + mt * 16 + quad * 4 + r;
        C[(size_t)m * N + n] = (OutT)(acc[mt][nt][r] + bv);
      }
    }
  }
}

struct WPtrs {
  const unsigned short* hi[5];
  const unsigned short* lo[5];
};

__global__ __launch_bounds__(256, 2)
void proj_gemm(const unsigned short* __restrict__ xhi,
               const unsigned short* __restrict__ xlo,
               WPtrs wp, float* __restrict__ outbase)
{
  int z = blockIdx.z;
  float* C = outbase + (size_t)z * ((size_t)M_ * DOUT);
  gemm_hilo_core<float>(xhi, xlo, wp.hi[z], wp.lo[z], C, nullptr,
                        DIN, DOUT, blockIdx.x * 128, blockIdx.y * 128);
}

__global__ __launch_bounds__(256, 2)
void final_gemm(const unsigned short* __restrict__ chi,
                const unsigned short* __restrict__ clo,
                const unsigned short* __restrict__ whi,
                const unsigned short* __restrict__ wlo,
                float* __restrict__ out, const float* __restrict__ bias)
{
  gemm_hilo_core<float>(chi, clo, whi, wlo, out, bias,
                        DOUT, DOUT, blockIdx.x * 128, blockIdx.y * 128);
}

// ---------------------------------------------------------------------------
// alpha[r,h] = exp(-exp(A_log[h]) * softplus(x[r]·Wa[h] + dt_bias[h]))
// ---------------------------------------------------------------------------
__global__ __launch_bounds__(256)
void alpha_kernel(const float* __restrict__ x,
                  const float* __restrict__ Wa,
                  const float* __restrict__ dtb,
                  const float* __restrict__ Alg,
                  float* __restrict__ alpha)
{
  __shared__ float WaS[16 * 1024];
  const int t = threadIdx.x;
#pragma unroll
  for (int i = 0; i < 16; i++) {
    int idx = (t + 256 * i) * 4;
    *(float4*)(&WaS[idx]) = *(const float4*)(Wa + idx);
  }
  __syncthreads();
  const int w = t >> 6, lane = t & 63;
  for (int r = blockIdx.x * 4 + w; r < M_; r += gridDim.x * 4) {
    const float* xr = x + (size_t)r * DIN + lane * 16;
    float xv[16];
#pragma unroll
    for (int j = 0; j < 4; j++) {
      float4 a = *(const float4*)(xr + j * 4);
      xv[j * 4 + 0] = a.x; xv[j * 4 + 1] = a.y; xv[j * 4 + 2] = a.z; xv[j * 4 + 3] = a.w;
    }
#pragma unroll 1
    for (int h = 0; h < 16; h++) {
      const float* wr = &WaS[h * 1024 + lane * 16];
      float p = 0.f;
#pragma unroll
      for (int j = 0; j < 4; j++) {
        float4 b = *(const float4*)(wr + j * 4);
        p += xv[j * 4 + 0] * b.x + xv[j * 4 + 1] * b.y +
             xv[j * 4 + 2] * b.z + xv[j * 4 + 3] * b.w;
      }
#pragma unroll
      for (int o = 32; o >= 1; o >>= 1) p += __shfl_xor(p, o, 64);
      if (lane == h) {
        float z = p + dtb[h];
        float sp = (z > 20.f) ? z : log1pf(expf(z));
        alpha[(size_t)r * 16 + h] = expf(-expf(Alg[h]) * sp);
      }
    }
  }
}

// ---------------------------------------------------------------------------
// In-place fp32: q <- q/||q||/8, k <- k/||k||, beta <- sigmoid(beta_raw).
// ---------------------------------------------------------------------------
__global__ __launch_bounds__(256)
void qkb_kernel(float* __restrict__ q,
                float* __restrict__ k,
                float* __restrict__ bta)
{
  const int t = threadIdx.x, w = t >> 6, lane = t & 63;
  const int NP = M_ * H_;
  for (int p = blockIdx.x * 4 + w; p < NP; p += gridDim.x * 4) {
    size_t off = (size_t)p * 64 + lane;
    float qv = q[off];
    float kv = k[off];
    float bv = bta[off];
    float qs = qv * qv, ks = kv * kv;
#pragma unroll
    for (int o = 32; o >= 1; o >>= 1) {
      qs += __shfl_xor(qs, o, 64);
      ks += __shfl_xor(ks, o, 64);
    }
    q[off] = qv * rsqrtf(qs) * 0.125f;
    k[off] = kv * rsqrtf(ks);
    bta[off] = 1.0f / (1.0f + expf(-bv));
  }
}

// ---------------------------------------------------------------------------
// Scan v6: 32-lane columns for 2 waves/SIMD. 2048 waves (512 blocks x 4):
// wave = (b,h,gg) with gg = part*4 + w (0..31); each 32-lane half owns
// e = gg*2 + half; lane i (0..31) holds d = 2i..2i+1 (float2 of state).
// d-reduce = 4 DPP + 1 ds_swizzle xor16 (within 32-lane groups).
// R1 post-mortem: stall (~181 cy/step) is memory latency, invariant to the
// arithmetic chain; at 1 wave/SIMD issue and stall never overlap. Doubling
// waves/SIMD lets one wave's stall hide under the other's issue.
// blockIdx = part*64 + bh keeps the 8 blocks of one (b,h) congruent mod 64
// -> same XCD -> shared L2 for the k,q rows.
// ---------------------------------------------------------------------------
#define WIN 8
__global__ __launch_bounds__(256, 2)
void scan_kernel(const float* __restrict__ q,
                 const float* __restrict__ k,
                 const float* __restrict__ v,
                 const float* __restrict__ bta,
                 const float* __restrict__ alpha,
                 float* __restrict__ ys)
{
  const int bl = blockIdx.x;
  const int bh = bl & 63;
  const int part = bl >> 6;                  // 0..7
  const int b = bh >> 4, h = bh & 15;
  const int w = threadIdx.x >> 6;
  const int lane = threadIdx.x & 63;
  const int gg = part * 4 + w;               // e-pair group 0..31
  const int half = lane >> 5;
  const int i = lane & 31;
  const int e = gg * 2 + half;

  const size_t rowstride = 1024;
  const size_t bhbase = (size_t)b * L_ * rowstride + (size_t)h * 64;
  const float* kp = k + bhbase + 2 * i;
  const float* qp = q + bhbase + 2 * i;
  const float* vp = v + bhbase + e;
  const float* bp = bta + bhbase + e;
  const float* ap = alpha + (size_t)b * L_ * 16 + h;

  float2 S = {0.f, 0.f};
  float Ya = 0.f, Yb = 0.f;

  float2 kA[WIN], qA[WIN]; float vA[WIN], bA[WIN], aA[WIN];
  float2 kB[WIN], qB[WIN]; float vB[WIN], bB[WIN], aB[WIN];

#define LOADW(KX, QX, VX, BX, AX, T0)                                     \
  {                                                                       \
    _Pragma("unroll")                                                     \
    for (int s = 0; s < WIN; s++) {                                       \
      int ts = (T0) + s; if (ts > L_ - 1) ts = L_ - 1;                    \
      size_t o = (size_t)ts * rowstride;                                  \
      KX[s] = *(const float2*)(kp + o);                                   \
      QX[s] = *(const float2*)(qp + o);                                   \
      VX[s] = vp[o]; BX[s] = bp[o]; AX[s] = ap[(size_t)ts * 16];          \
    }                                                                     \
  }

#define COMPW(KX, QX, VX, BX, AX, T0, YACC)                               \
  {                                                                       \
    _Pragma("unroll")                                                     \
    for (int tt = 0; tt < WIN; tt++) {                                    \
      float2 kc = KX[tt], qc = QX[tt];                                    \
      float vc = VX[tt], bc = BX[tt], ac = AX[tt];                        \
      float p = kc.x * S.x + kc.y * S.y;                                  \
      p = row32_allreduce(p);                                             \
      float delta = (vc - ac * p) * bc;                                   \
      S.x = fmaf(ac, S.x, kc.x * delta);                                  \
      S.y = fmaf(ac, S.y, kc.y * delta);                                  \
      float yp = qc.x * S.x + qc.y * S.y;                                 \
      yp = row32_allreduce(yp);                                           \
      if (i == tt) YACC = yp;                                             \
    }                                                                     \
    if (i < WIN)                                                          \
      ys[bhbase + (size_t)((T0) + i) * rowstride + e] = YACC;             \
  }

  LOADW(kA, qA, vA, bA, aA, 0);
  for (int w0 = 0; w0 < L_; w0 += 2 * WIN) {
    LOADW(kB, qB, vB, bB, aB, w0 + WIN);
    COMPW(kA, qA, vA, bA, aA, w0, Ya);
    LOADW(kA, qA, vA, bA, aA, w0 + 2 * WIN);
    COMPW(kB, qB, vB, bB, aB, w0 + WIN, Yb);
  }
#undef LOADW
#undef COMPW
}

// ---------------------------------------------------------------------------
// ctx = rmsnorm(ys, norm_w) * silu(gate), written directly as hi/lo bf16
// (fuses the ctx cast_hilo pass: saves one 67 MB kernel).
// ---------------------------------------------------------------------------
__global__ __launch_bounds__(256)
void out_gate_kernel(const float* __restrict__ ys,
                     const float* __restrict__ g,
                     const float* __restrict__ norm_w,
                     unsigned short* __restrict__ chi,
                     unsigned short* __restrict__ clo)
{
  const int t = threadIdx.x, w = t >> 6, lane = t & 63;
  const int NP = M_ * H_;
  float nw = norm_w[lane];
  for (int p = blockIdx.x * 4 + w; p < NP; p += gridDim.x * 4) {
    size_t off = (size_t)p * 64 + lane;
    float y = ys[off];
    float gv = g[off];
    float s = y * y;
#pragma unroll
    for (int o = 32; o >= 1; o >>= 1) s += __shfl_xor(s, o, 64);
    float rs = rsqrtf(s * (1.0f / 64.0f) + 1e-6f);
    float silu = gv / (1.0f + expf(-gv));
    float c = y * rs * nw * silu;
    unsigned short hh = f2bf(c);
    chi[off] = hh;
    clo[off] = f2bf(c - bf2f(hh));
  }
}

// ---------------------------------------------------------------------------
extern "C" void kernel_launch(void* const* d_in, const int* in_sizes, int n_in,
                              void* d_out, int out_size, void* d_ws, size_t ws_size,
                              hipStream_t stream)
{
  const float* x   = (const float*)d_in[0];
  const float* Wq  = (const float*)d_in[1];
  const float* Wk  = (const float*)d_in[2];
  const float* Wv  = (const float*)d_in[3];
  const float* Wg  = (const float*)d_in[4];
  const float* Wb  = (const float*)d_in[5];
  const float* Wa  = (const float*)d_in[6];
  const float* dtb = (const float*)d_in[7];
  const float* Alg = (const float*)d_in[8];
  const float* nw  = (const float*)d_in[9];
  const float* Wo  = (const float*)d_in[10];
  const float* bo  = (const float*)d_in[11];

  const size_t TSZ = (size_t)M_ * DOUT;   // 8,388,608
  const size_t WSZ = (size_t)DOUT * DIN;  // 1,048,576

  float* q    = (float*)d_ws;             // projections q,k,v,g,bta contiguous
  float* k    = q + TSZ;
  float* v    = k + TSZ;
  float* g    = v + TSZ;
  float* bta  = g + TSZ;
  float* ys   = bta + TSZ;
  float* alph = ys + TSZ;                 // M_*H_ floats
  unsigned short* whl = (unsigned short*)(alph + (size_t)M_ * H_);
  unsigned short* whi[6], *wlo[6];
  for (int j = 0; j < 6; j++) { whi[j] = whl + (size_t)(2 * j) * WSZ; wlo[j] = whl + (size_t)(2 * j + 1) * WSZ; }
  // x hi/lo aliased into ys region (dead until scan)
  unsigned short* xhi = (unsigned short*)ys;
  unsigned short* xlo = xhi + TSZ;
  // ctx hi/lo aliased into q region (q dead after scan)
  unsigned short* chi = (unsigned short*)q;
  unsigned short* clo = chi + TSZ;
  float* outp = (float*)d_out;

  cast_hilo<<<2048, 256, 0, stream>>>(x, xhi, xlo, (int)TSZ);
  cast_hilo<<<512, 256, 0, stream>>>(Wq, whi[0], wlo[0], (int)WSZ);
  cast_hilo<<<512, 256, 0, stream>>>(Wk, whi[1], wlo[1], (int)WSZ);
  cast_hilo<<<512, 256, 0, stream>>>(Wv, whi[2], wlo[2], (int)WSZ);
  cast_hilo<<<512, 256, 0, stream>>>(Wg, whi[3], wlo[3], (int)WSZ);
  cast_hilo<<<512, 256, 0, stream>>>(Wb, whi[4], wlo[4], (int)WSZ);
  cast_hilo<<<512, 256, 0, stream>>>(Wo, whi[5], wlo[5], (int)WSZ);

  WPtrs wp;
  for (int j = 0; j < 5; j++) { wp.hi[j] = whi[j]; wp.lo[j] = wlo[j]; }
  dim3 gp(M_ / 128, DOUT / 128, 5);
  proj_gemm<<<gp, 256, 0, stream>>>(xhi, xlo, wp, q);

  alpha_kernel<<<128, 256, 0, stream>>>(x, Wa, dtb, Alg, alph);
  qkb_kernel<<<1024, 256, 0, stream>>>(q, k, bta);
  scan_kernel<<<512, 256, 0, stream>>>(q, k, v, bta, alph, ys);
  out_gate_kernel<<<1024, 256, 0, stream>>>(ys, g, nw, chi, clo);

  dim3 gf(M_ / 128, DOUT / 128);
  final_gemm<<<gf, 256, 0, stream>>>(chi, clo, whi[5], wlo[5], outp, bo);
}

// Round 5
// 1000.864 us; speedup vs baseline: 1.0255x; 1.0255x over previous
//
#include <hip/hip_runtime.h>

// Problem constants
#define B_   4
#define L_   2048
#define DIN  1024
#define DOUT 1024
#define H_   16
#define DH_  64
#define M_   (B_ * L_)   // 8192 rows

typedef __bf16 bf16x8 __attribute__((ext_vector_type(8)));
typedef float  f32x4  __attribute__((ext_vector_type(4)));
typedef unsigned u32x2 __attribute__((ext_vector_type(2)));

__device__ __forceinline__ float bf2f(unsigned short u) {
  union { unsigned int i; float f; } x; x.i = ((unsigned int)u) << 16; return x.f;
}
__device__ __forceinline__ unsigned short f2bf(float f) {
  union { float f; unsigned int i; } x; x.f = f;
  unsigned int r = x.i + 0x7FFFu + ((x.i >> 16) & 1u);
  return (unsigned short)(r >> 16);
}

// DPP cross-lane add (VALU latency, no DS pipe). 0xB1=quad_perm[1,0,3,2],
// 0x4E=quad_perm[2,3,0,1], 0x124=row_ror:4, 0x128=row_ror:8 -> 16-lane allreduce.
template <int CTRL>
__device__ __forceinline__ float dpp_add(float x) {
  int v = __builtin_amdgcn_update_dpp(0, __float_as_int(x), CTRL, 0xF, 0xF, false);
  return x + __int_as_float(v);
}
// Column allreduce for e-columns laid out on 16-rows {0,2} (e0) / {1,3} (e1):
// 4-step DPP row16 allreduce -> every lane holds its 16-row total; then
// __builtin_amdgcn_permlane32_swap(x,x) returns {d,s} with d+s = x + x^32 in
// every lane: r0/r2 lanes get total(r0)+total(r2), r1/r3 get total(r1)+
// total(r3). Pure VALU, compiler handles the permlane hazard wait-states
// (R3/R4 post-mortem: hand asm hit register-coalescing, then the documented
// VALU->permlane operand hazard; the builtin sidesteps both).
__device__ __forceinline__ float col32_allreduce(float x) {
  x = dpp_add<0xB1>(x);
  x = dpp_add<0x4E>(x);
  x = dpp_add<0x124>(x);
  x = dpp_add<0x128>(x);
  u32x2 r = __builtin_amdgcn_permlane32_swap(__float_as_uint(x), __float_as_uint(x), false, false);
  return __uint_as_float(r[0]) + __uint_as_float(r[1]);
}

// ---------------------------------------------------------------------------
// fp32 -> (hi, lo) bf16 split: hi = bf16(x), lo = bf16(x - hi).
// ---------------------------------------------------------------------------
__global__ __launch_bounds__(256)
void cast_hilo(const float* __restrict__ in,
               unsigned short* __restrict__ hi,
               unsigned short* __restrict__ lo, int n)
{
  int i = (blockIdx.x * 256 + threadIdx.x) * 8;
  int stride = gridDim.x * 256 * 8;
  for (; i < n; i += stride) {
    float4 a = *(const float4*)(in + i);
    float4 b = *(const float4*)(in + i + 4);
    float v[8] = {a.x, a.y, a.z, a.w, b.x, b.y, b.z, b.w};
    ushort4 h0, h1, l0, l1;
    unsigned short hh[8], ll[8];
#pragma unroll
    for (int j = 0; j < 8; j++) {
      hh[j] = f2bf(v[j]);
      ll[j] = f2bf(v[j] - bf2f(hh[j]));
    }
    h0 = {hh[0], hh[1], hh[2], hh[3]}; h1 = {hh[4], hh[5], hh[6], hh[7]};
    l0 = {ll[0], ll[1], ll[2], ll[3]}; l1 = {ll[4], ll[5], ll[6], ll[7]};
    *(ushort4*)(hi + i) = h0; *(ushort4*)(hi + i + 4) = h1;
    *(ushort4*)(lo + i) = l0; *(ushort4*)(lo + i + 4) = l1;
  }
}

// ---------------------------------------------------------------------------
// GEMM core: C[M,N] = A[M,K] @ W[N,K]^T (+bias), A/W as hi/lo bf16 pairs.
// acc = hi*hi + lo*hi + hi*lo (3 MFMAs). 128x128 tile, BK=64, 4 waves 2x2.
// LDS rows padded to 72 ushort (144 B = 36 banks): consecutive rows shift by
// 4 banks, so the 16-lane fragment read (same col, rows r..r+15) is 2-way max
// (free) instead of the 16-way conflict (5.7x) of an unpadded 128 B stride.
// ---------------------------------------------------------------------------
#define LPAD 72
template <typename OutT>
__device__ __forceinline__
void gemm_hilo_core(const unsigned short* __restrict__ Ahi,
                    const unsigned short* __restrict__ Alo,
                    const unsigned short* __restrict__ Whi,
                    const unsigned short* __restrict__ Wlo,
                    OutT* __restrict__ C,
                    const float* __restrict__ bias,
                    int K, int N, int m0, int n0)
{
  __shared__ unsigned short AsH[128][LPAD];
  __shared__ unsigned short AsL[128][LPAD];
  __shared__ unsigned short BsH[128][LPAD];
  __shared__ unsigned short BsL[128][LPAD];
  const int t = threadIdx.x;
  const int w = t >> 6;
  const int lane = t & 63;
  const int wm = (w >> 1) * 64, wn = (w & 1) * 64;
  const int l15 = lane & 15, quad = lane >> 4;

  f32x4 acc[4][4] = {};

  for (int k0 = 0; k0 < K; k0 += 64) {
#pragma unroll
    for (int i = 0; i < 4; i++) {
      int c = t + 256 * i;
      int row = c >> 3;
      int col = (c & 7) * 8;
      size_t ga = (size_t)(m0 + row) * K + k0 + col;
      size_t gb = (size_t)(n0 + row) * K + k0 + col;
      *(uint4*)(&AsH[row][col]) = *(const uint4*)(Ahi + ga);
      *(uint4*)(&AsL[row][col]) = *(const uint4*)(Alo + ga);
      *(uint4*)(&BsH[row][col]) = *(const uint4*)(Whi + gb);
      *(uint4*)(&BsL[row][col]) = *(const uint4*)(Wlo + gb);
    }
    __syncthreads();
#pragma unroll
    for (int kh = 0; kh < 2; kh++) {
      bf16x8 ah[4], al[4], bh[4], bl[4];
#pragma unroll
      for (int i = 0; i < 4; i++) {
        union U { uint4 u; bf16x8 v; } u0, u1, u2, u3;
        u0.u = *(const uint4*)(&AsH[wm + i * 16 + l15][kh * 32 + quad * 8]);
        u1.u = *(const uint4*)(&AsL[wm + i * 16 + l15][kh * 32 + quad * 8]);
        u2.u = *(const uint4*)(&BsH[wn + i * 16 + l15][kh * 32 + quad * 8]);
        u3.u = *(const uint4*)(&BsL[wn + i * 16 + l15][kh * 32 + quad * 8]);
        ah[i] = u0.v; al[i] = u1.v; bh[i] = u2.v; bl[i] = u3.v;
      }
#pragma unroll
      for (int mt = 0; mt < 4; mt++)
#pragma unroll
        for (int nt = 0; nt < 4; nt++) {
          acc[mt][nt] = __builtin_amdgcn_mfma_f32_16x16x32_bf16(ah[mt], bh[nt], acc[mt][nt], 0, 0, 0);
          acc[mt][nt] = __builtin_amdgcn_mfma_f32_16x16x32_bf16(al[mt], bh[nt], acc[mt][nt], 0, 0, 0);
          acc[mt][nt] = __builtin_amdgcn_mfma_f32_16x16x32_bf16(ah[mt], bl[nt], acc[mt][nt], 0, 0, 0);
        }
    }
    __syncthreads();
  }

#pragma unroll
  for (int mt = 0; mt < 4; mt++) {
#pragma unroll
    for (int nt = 0; nt < 4; nt++) {
      int n = n0 + wn + nt * 16 + l15;
      float bv = bias ? bias[n] : 0.0f;
#pragma unroll
      for (int r = 0; r < 4; r++) {
        int m = m0 + wm + mt * 16 + quad * 4 + r;
        C[(size_t)m * N + n] = (OutT)(acc[mt][nt][r] + bv);
      }
    }
  }
}

struct WPtrs {
  const unsigned short* hi[5];
  const unsigned short* lo[5];
};

__global__ __launch_bounds__(256, 2)
void proj_gemm(const unsigned short* __restrict__ xhi,
               const unsigned short* __restrict__ xlo,
               WPtrs wp, float* __restrict__ outbase)
{
  int z = blockIdx.z;
  float* C = outbase + (size_t)z * ((size_t)M_ * DOUT);
  gemm_hilo_core<float>(xhi, xlo, wp.hi[z], wp.lo[z], C, nullptr,
                        DIN, DOUT, blockIdx.x * 128, blockIdx.y * 128);
}

__global__ __launch_bounds__(256, 2)
void final_gemm(const unsigned short* __restrict__ chi,
                const unsigned short* __restrict__ clo,
                const unsigned short* __restrict__ whi,
                const unsigned short* __restrict__ wlo,
                float* __restrict__ out, const float* __restrict__ bias)
{
  gemm_hilo_core<float>(chi, clo, whi, wlo, out, bias,
                        DOUT, DOUT, blockIdx.x * 128, blockIdx.y * 128);
}

// ---------------------------------------------------------------------------
// alpha[r,h] = exp(-exp(A_log[h]) * softplus(x[r]·Wa[h] + dt_bias[h]))
// ---------------------------------------------------------------------------
__global__ __launch_bounds__(256)
void alpha_kernel(const float* __restrict__ x,
                  const float* __restrict__ Wa,
                  const float* __restrict__ dtb,
                  const float* __restrict__ Alg,
                  float* __restrict__ alpha)
{
  __shared__ float WaS[16 * 1024];
  const int t = threadIdx.x;
#pragma unroll
  for (int i = 0; i < 16; i++) {
    int idx = (t + 256 * i) * 4;
    *(float4*)(&WaS[idx]) = *(const float4*)(Wa + idx);
  }
  __syncthreads();
  const int w = t >> 6, lane = t & 63;
  for (int r = blockIdx.x * 4 + w; r < M_; r += gridDim.x * 4) {
    const float* xr = x + (size_t)r * DIN + lane * 16;
    float xv[16];
#pragma unroll
    for (int j = 0; j < 4; j++) {
      float4 a = *(const float4*)(xr + j * 4);
      xv[j * 4 + 0] = a.x; xv[j * 4 + 1] = a.y; xv[j * 4 + 2] = a.z; xv[j * 4 + 3] = a.w;
    }
#pragma unroll 1
    for (int h = 0; h < 16; h++) {
      const float* wr = &WaS[h * 1024 + lane * 16];
      float p = 0.f;
#pragma unroll
      for (int j = 0; j < 4; j++) {
        float4 b = *(const float4*)(wr + j * 4);
        p += xv[j * 4 + 0] * b.x + xv[j * 4 + 1] * b.y +
             xv[j * 4 + 2] * b.z + xv[j * 4 + 3] * b.w;
      }
#pragma unroll
      for (int o = 32; o >= 1; o >>= 1) p += __shfl_xor(p, o, 64);
      if (lane == h) {
        float z = p + dtb[h];
        float sp = (z > 20.f) ? z : log1pf(expf(z));
        alpha[(size_t)r * 16 + h] = expf(-expf(Alg[h]) * sp);
      }
    }
  }
}

// ---------------------------------------------------------------------------
// In-place fp32: q <- q/||q||/8, k <- k/||k||, beta <- sigmoid(beta_raw).
// ---------------------------------------------------------------------------
__global__ __launch_bounds__(256)
void qkb_kernel(float* __restrict__ q,
                float* __restrict__ k,
                float* __restrict__ bta)
{
  const int t = threadIdx.x, w = t >> 6, lane = t & 63;
  const int NP = M_ * H_;
  for (int p = blockIdx.x * 4 + w; p < NP; p += gridDim.x * 4) {
    size_t off = (size_t)p * 64 + lane;
    float qv = q[off];
    float kv = k[off];
    float bv = bta[off];
    float qs = qv * qv, ks = kv * kv;
#pragma unroll
    for (int o = 32; o >= 1; o >>= 1) {
      qs += __shfl_xor(qs, o, 64);
      ks += __shfl_xor(ks, o, 64);
    }
    q[off] = qv * rsqrtf(qs) * 0.125f;
    k[off] = kv * rsqrtf(ks);
    bta[off] = 1.0f / (1.0f + expf(-bv));
  }
}

// ---------------------------------------------------------------------------
// Scan v9: 32-lane columns (2048 waves = 2 waves/SIMD) + pure-VALU allreduce
// + depth-2 prefetch (4 rotating WIN=4 buffers, statically indexed).
// Column layout chosen so the cross-row exchange is permlane32_swap (verified
// builtin): wave handles 2 e-columns, e0 on 16-rows {0,2}, e1 on rows {1,3}.
// col = (lane>>4)&1; within-column index i = (lane&15) | ((lane>>5)<<4),
// lane holds d = 2i..2i+1. col32_allreduce = 4 DPP (row16) + permlane32_swap.
// blockIdx = part*64+bh keeps the 8 blocks of one (b,h) congruent mod 64 ->
// same XCD -> shared L2 for the k,q rows.
// ---------------------------------------------------------------------------
#define WIN 4
__global__ __launch_bounds__(256, 2)
void scan_kernel(const float* __restrict__ q,
                 const float* __restrict__ k,
                 const float* __restrict__ v,
                 const float* __restrict__ bta,
                 const float* __restrict__ alpha,
                 float* __restrict__ ys)
{
  const int bl = blockIdx.x;
  const int bh = bl & 63;
  const int part = bl >> 6;                  // 0..7
  const int b = bh >> 4, h = bh & 15;
  const int w = threadIdx.x >> 6;
  const int lane = threadIdx.x & 63;
  const int gg = part * 4 + w;               // e-pair group 0..31
  const int col = (lane >> 4) & 1;           // which e of the pair
  const int i = (lane & 15) | ((lane >> 5) << 4);  // 0..31 within column
  const int e = gg * 2 + col;

  const size_t rowstride = 1024;
  const size_t bhbase = (size_t)b * L_ * rowstride + (size_t)h * 64;
  const float* kp = k + bhbase + 2 * i;
  const float* qp = q + bhbase + 2 * i;
  const float* vp = v + bhbase + e;
  const float* bp = bta + bhbase + e;
  const float* ap = alpha + (size_t)b * L_ * 16 + h;

  float2 S = {0.f, 0.f};
  float Ya = 0.f, Yb = 0.f, Yc = 0.f, Yd = 0.f;

  float2 kA[WIN], qA[WIN]; float vA[WIN], bA[WIN], aA[WIN];
  float2 kB[WIN], qB[WIN]; float vB[WIN], bB[WIN], aB[WIN];
  float2 kC[WIN], qC[WIN]; float vC[WIN], bC[WIN], aC[WIN];
  float2 kD[WIN], qD[WIN]; float vD[WIN], bD[WIN], aD[WIN];

#define LOADW(KX, QX, VX, BX, AX, T0)                                     \
  {                                                                       \
    _Pragma("unroll")                                                     \
    for (int s = 0; s < WIN; s++) {                                       \
      int ts = (T0) + s; if (ts > L_ - 1) ts = L_ - 1;                    \
      size_t o = (size_t)ts * rowstride;                                  \
      KX[s] = *(const float2*)(kp + o);                                   \
      QX[s] = *(const float2*)(qp + o);                                   \
      VX[s] = vp[o]; BX[s] = bp[o]; AX[s] = ap[(size_t)ts * 16];          \
    }                                                                     \
  }

#define COMPW(KX, QX, VX, BX, AX, T0, YACC)                               \
  {                                                                       \
    _Pragma("unroll")                                                     \
    for (int tt = 0; tt < WIN; tt++) {                                    \
      float2 kc = KX[tt], qc = QX[tt];                                    \
      float vc = VX[tt], bc = BX[tt], ac = AX[tt];                        \
      float p = kc.x * S.x + kc.y * S.y;                                  \
      p = col32_allreduce(p);                                             \
      float delta = (vc - ac * p) * bc;                                   \
      S.x = fmaf(ac, S.x, kc.x * delta);                                  \
      S.y = fmaf(ac, S.y, kc.y * delta);                                  \
      float yp = qc.x * S.x + qc.y * S.y;                                 \
      yp = col32_allreduce(yp);                                           \
      if (i == tt) YACC = yp;                                             \
    }                                                                     \
    if (i < WIN)                                                          \
      ys[bhbase + (size_t)((T0) + i) * rowstride + e] = YACC;             \
  }

  LOADW(kA, qA, vA, bA, aA, 0);
  LOADW(kB, qB, vB, bB, aB, WIN);
  for (int w0 = 0; w0 < L_; w0 += 4 * WIN) {
    LOADW(kC, qC, vC, bC, aC, w0 + 2 * WIN);
    COMPW(kA, qA, vA, bA, aA, w0, Ya);
    LOADW(kD, qD, vD, bD, aD, w0 + 3 * WIN);
    COMPW(kB, qB, vB, bB, aB, w0 + WIN, Yb);
    LOADW(kA, qA, vA, bA, aA, w0 + 4 * WIN);
    COMPW(kC, qC, vC, bC, aC, w0 + 2 * WIN, Yc);
    LOADW(kB, qB, vB, bB, aB, w0 + 5 * WIN);
    COMPW(kD, qD, vD, bD, aD, w0 + 3 * WIN, Yd);
  }
#undef LOADW
#undef COMPW
}

// ---------------------------------------------------------------------------
// ctx = rmsnorm(ys, norm_w) * silu(gate), written directly as hi/lo bf16
// (fuses the ctx cast_hilo pass: saves one 67 MB kernel).
// ---------------------------------------------------------------------------
__global__ __launch_bounds__(256)
void out_gate_kernel(const float* __restrict__ ys,
                     const float* __restrict__ g,
                     const float* __restrict__ norm_w,
                     unsigned short* __restrict__ chi,
                     unsigned short* __restrict__ clo)
{
  const int t = threadIdx.x, w = t >> 6, lane = t & 63;
  const int NP = M_ * H_;
  float nw = norm_w[lane];
  for (int p = blockIdx.x * 4 + w; p < NP; p += gridDim.x * 4) {
    size_t off = (size_t)p * 64 + lane;
    float y = ys[off];
    float gv = g[off];
    float s = y * y;
#pragma unroll
    for (int o = 32; o >= 1; o >>= 1) s += __shfl_xor(s, o, 64);
    float rs = rsqrtf(s * (1.0f / 64.0f) + 1e-6f);
    float silu = gv / (1.0f + expf(-gv));
    float c = y * rs * nw * silu;
    unsigned short hh = f2bf(c);
    chi[off] = hh;
    clo[off] = f2bf(c - bf2f(hh));
  }
}

// ---------------------------------------------------------------------------
extern "C" void kernel_launch(void* const* d_in, const int* in_sizes, int n_in,
                              void* d_out, int out_size, void* d_ws, size_t ws_size,
                              hipStream_t stream)
{
  const float* x   = (const float*)d_in[0];
  const float* Wq  = (const float*)d_in[1];
  const float* Wk  = (const float*)d_in[2];
  const float* Wv  = (const float*)d_in[3];
  const float* Wg  = (const float*)d_in[4];
  const float* Wb  = (const float*)d_in[5];
  const float* Wa  = (const float*)d_in[6];
  const float* dtb = (const float*)d_in[7];
  const float* Alg = (const float*)d_in[8];
  const float* nw  = (const float*)d_in[9];
  const float* Wo  = (const float*)d_in[10];
  const float* bo  = (const float*)d_in[11];

  const size_t TSZ = (size_t)M_ * DOUT;   // 8,388,608
  const size_t WSZ = (size_t)DOUT * DIN;  // 1,048,576

  float* q    = (float*)d_ws;             // projections q,k,v,g,bta contiguous
  float* k    = q + TSZ;
  float* v    = k + TSZ;
  float* g    = v + TSZ;
  float* bta  = g + TSZ;
  float* ys   = bta + TSZ;
  float* alph = ys + TSZ;                 // M_*H_ floats
  unsigned short* whl = (unsigned short*)(alph + (size_t)M_ * H_);
  unsigned short* whi[6], *wlo[6];
  for (int j = 0; j < 6; j++) { whi[j] = whl + (size_t)(2 * j) * WSZ; wlo[j] = whl + (size_t)(2 * j + 1) * WSZ; }
  // x hi/lo aliased into ys region (dead until scan)
  unsigned short* xhi = (unsigned short*)ys;
  unsigned short* xlo = xhi + TSZ;
  // ctx hi/lo aliased into q region (q dead after scan)
  unsigned short* chi = (unsigned short*)q;
  unsigned short* clo = chi + TSZ;
  float* outp = (float*)d_out;

  cast_hilo<<<2048, 256, 0, stream>>>(x, xhi, xlo, (int)TSZ);
  cast_hilo<<<512, 256, 0, stream>>>(Wq, whi[0], wlo[0], (int)WSZ);
  cast_hilo<<<512, 256, 0, stream>>>(Wk, whi[1], wlo[1], (int)WSZ);
  cast_hilo<<<512, 256, 0, stream>>>(Wv, whi[2], wlo[2], (int)WSZ);
  cast_hilo<<<512, 256, 0, stream>>>(Wg, whi[3], wlo[3], (int)WSZ);
  cast_hilo<<<512, 256, 0, stream>>>(Wb, whi[4], wlo[4], (int)WSZ);
  cast_hilo<<<512, 256, 0, stream>>>(Wo, whi[5], wlo[5], (int)WSZ);

  WPtrs wp;
  for (int j = 0; j < 5; j++) { wp.hi[j] = whi[j]; wp.lo[j] = wlo[j]; }
  dim3 gp(M_ / 128, DOUT / 128, 5);
  proj_gemm<<<gp, 256, 0, stream>>>(xhi, xlo, wp, q);

  alpha_kernel<<<128, 256, 0, stream>>>(x, Wa, dtb, Alg, alph);
  qkb_kernel<<<1024, 256, 0, stream>>>(q, k, bta);
  scan_kernel<<<512, 256, 0, stream>>>(q, k, v, bta, alph, ys);
  out_gate_kernel<<<1024, 256, 0, stream>>>(ys, g, nw, chi, clo);

  dim3 gf(M_ / 128, DOUT / 128);
  final_gemm<<<gf, 256, 0, stream>>>(chi, clo, whi[5], wlo[5], outp, bo);
}